// Round 1
// baseline (1048.628 us; speedup 1.0000x reference)
//
#include <hip/hip_runtime.h>

// topk cross-entropy: N=262144 rows, C=128 classes, k = floor(0.7*N).
// Pass 1 (dominant): 128 MiB read -> per-row NLL + hi16 histogram.
// Then exact radix-select of the k-th largest via two 16-bit histogram scans,
// then tie-exact mean = (sum_{v>t} v + (k - cnt_gt)*t) / k.

#define NCLASS 128

struct Scalars {
  unsigned sel_hi;        // hi16 bin containing k-th largest
  unsigned cnt_above_hi;  // count with hi16 > sel_hi
  int krem;               // remaining rank within sel_hi bin
  int cnt_gt;             // count strictly greater than threshold
  float thr;              // k-th largest value (exact bits)
  unsigned pad;
  double sum_gt;          // sum of values strictly greater than threshold
};

// One wave per row: lane l holds elements 2l, 2l+1 (float2, coalesced 8B/lane).
__global__ void loss_hist_kernel(const float* __restrict__ x,
                                 const int* __restrict__ tgt,
                                 float* __restrict__ losses,
                                 unsigned* __restrict__ hist_hi, int N) {
  int lane = threadIdx.x & 63;
  int row = blockIdx.x * 4 + (threadIdx.x >> 6);
  if (row >= N) return;
  const float2 v = reinterpret_cast<const float2*>(x + (size_t)row * NCLASS)[lane];
  float m = fmaxf(v.x, v.y);
#pragma unroll
  for (int o = 32; o > 0; o >>= 1) m = fmaxf(m, __shfl_xor(m, o, 64));
  float s = __expf(v.x - m) + __expf(v.y - m);
#pragma unroll
  for (int o = 32; o > 0; o >>= 1) s += __shfl_xor(s, o, 64);
  if (lane == 0) {
    float xt = x[(size_t)row * NCLASS + tgt[row]];   // L1 hit (row just streamed)
    float loss = __logf(s) + m - xt;
    loss = fmaxf(loss, 0.0f);                        // guard tiny negative from approx log
    losses[row] = loss;
    atomicAdd(&hist_hi[__float_as_uint(loss) >> 16], 1u);
  }
}

// Single-block descending scan over a 65536-bin histogram.
// phase 0: find hi16 bin for rank K.  phase 1: find lo16 bin for rank sc->krem.
__global__ void scan_kernel(const unsigned* __restrict__ hist, Scalars* sc,
                            int K, int phase) {
  __shared__ unsigned csum[256];
  int t = threadIdx.x;
  unsigned s = 0;
  for (int i = 0; i < 256; ++i) s += hist[t * 256 + i];
  csum[t] = s;
  __syncthreads();
  if (t == 0) {
    long long Ktar = (phase == 0) ? (long long)K : (long long)sc->krem;
    long long acc = 0;
    int chunk = 0;
    for (int c = 255; c >= 0; --c) {
      if (acc + (long long)csum[c] >= Ktar) { chunk = c; break; }
      acc += csum[c];
    }
    int bin = chunk * 256;
    for (int b = chunk * 256 + 255; b >= chunk * 256; --b) {
      unsigned hb = hist[b];
      if (acc + (long long)hb >= Ktar) { bin = b; break; }
      acc += hb;
    }
    // acc == count strictly above `bin`
    if (phase == 0) {
      sc->sel_hi = (unsigned)bin;
      sc->cnt_above_hi = (unsigned)acc;
      sc->krem = (int)(Ktar - acc);
    } else {
      unsigned tb = (sc->sel_hi << 16) | (unsigned)bin;
      sc->thr = __uint_as_float(tb);
      sc->cnt_gt = (int)(sc->cnt_above_hi + (unsigned)acc);
    }
  }
}

__global__ void hist_lo_kernel(const float* __restrict__ losses,
                               const Scalars* __restrict__ sc,
                               unsigned* __restrict__ hist_lo, int N) {
  int idx = blockIdx.x * blockDim.x + threadIdx.x;
  if (idx >= N) return;
  unsigned sel = sc->sel_hi;
  unsigned bits = __float_as_uint(losses[idx]);
  if ((bits >> 16) == sel) atomicAdd(&hist_lo[bits & 0xffffu], 1u);
}

__global__ void sum_gt_kernel(const float* __restrict__ losses, Scalars* sc, int N) {
  int idx = blockIdx.x * blockDim.x + threadIdx.x;
  unsigned tb = __float_as_uint(sc->thr);
  float v = 0.0f;
  if (idx < N) {
    float l = losses[idx];
    if (__float_as_uint(l) > tb) v = l;
  }
#pragma unroll
  for (int o = 32; o > 0; o >>= 1) v += __shfl_xor(v, o, 64);
  if ((threadIdx.x & 63) == 0) atomicAdd(&sc->sum_gt, (double)v);
}

__global__ void finalize_kernel(const Scalars* __restrict__ sc, float* out, int K) {
  double mean = (sc->sum_gt + (double)(K - sc->cnt_gt) * (double)sc->thr) / (double)K;
  *out = (float)mean;
}

extern "C" void kernel_launch(void* const* d_in, const int* in_sizes, int n_in,
                              void* d_out, int out_size, void* d_ws, size_t ws_size,
                              hipStream_t stream) {
  const float* x = (const float*)d_in[0];
  const int* tgt = (const int*)d_in[1];
  float* out = (float*)d_out;
  int N = in_sizes[1];                       // 262144 rows
  int K = (int)(0.7 * (double)N);            // matches Python int(0.7*N) = 183500

  char* ws = (char*)d_ws;
  float* losses = (float*)ws;                                     // N*4 B
  unsigned* hist_hi = (unsigned*)(ws + (size_t)N * 4);            // 256 KiB
  unsigned* hist_lo = hist_hi + 65536;                            // 256 KiB
  Scalars* sc = (Scalars*)(ws + (size_t)N * 4 + 2u * 65536u * 4u);

  // zero histograms + scalar block (ws is poisoned 0xAA before every call)
  hipMemsetAsync(hist_hi, 0, 2u * 65536u * 4u + sizeof(Scalars), stream);

  loss_hist_kernel<<<(N + 3) / 4, 256, 0, stream>>>(x, tgt, losses, hist_hi, N);
  scan_kernel<<<1, 256, 0, stream>>>(hist_hi, sc, K, 0);
  hist_lo_kernel<<<(N + 255) / 256, 256, 0, stream>>>(losses, sc, hist_lo, N);
  scan_kernel<<<1, 256, 0, stream>>>(hist_lo, sc, K, 1);
  sum_gt_kernel<<<(N + 255) / 256, 256, 0, stream>>>(losses, sc, N);
  finalize_kernel<<<1, 1, 0, stream>>>(sc, out, K);
}

// Round 2
// 228.151 us; speedup vs baseline: 4.5962x; 4.5962x over previous
//
#include <hip/hip_runtime.h>

// topk cross-entropy: N=262144 rows, C=128 classes, K = int(0.7*N) = 183500.
// Round 2: kill same-address atomic contention.
//  - loss pass: 8 rows/wave (16 f32/lane), LDS-privatized 4096-bin (bits>>20)
//    histogram, flushed to 8 replicated global hists (<=64 atomics/address).
//  - exact k-th largest via 12/10/10-bit radix select (losses >= 0 so float
//    bits are monotone), two cheap refine passes over the 1 MiB loss array.
//  - tie-exact mean: (sum_{v>thr} v + (K - cnt_gt)*thr) / K.

#define NCLASS 128
#define NREP 8

struct Scalars {
  unsigned sel1, sel2;
  unsigned cnt_above;   // cumulative count strictly above current prefix
  int krem;             // remaining rank within current prefix
  unsigned thr_bits;    // final: bit pattern of k-th largest
  unsigned pad[11];
};

__device__ __forceinline__ unsigned suffix_incl_u(unsigned x, int lane) {
#pragma unroll
  for (int off = 1; off < 64; off <<= 1) {
    unsigned v = __shfl_down(x, off, 64);
    if (lane + off < 64) x += v;
  }
  return x;
}

__global__ __launch_bounds__(256) void loss_hist_kernel(
    const float* __restrict__ x, const int* __restrict__ tgt,
    float* __restrict__ losses, unsigned* __restrict__ hist1, int N) {
  __shared__ unsigned lh[4096];
  for (int i = threadIdx.x; i < 4096; i += 256) lh[i] = 0;
  __syncthreads();

  const int lane = threadIdx.x & 63;
  const int j = lane & 7;        // position within row (owns float4 j, j+8, j+16, j+24)
  const int r = lane >> 3;       // row within the wave's 8-row group
  const int gw = blockIdx.x * 4 + (threadIdx.x >> 6);
  const int W = gridDim.x * 4;   // total waves

  for (int base = gw; base * 8 < N; base += W) {
    const int row = base * 8 + r;
    const float4* rp = (const float4*)(x + (size_t)row * NCLASS);
    float4 a = rp[j];
    float4 b = rp[j + 8];
    float4 c = rp[j + 16];
    float4 d = rp[j + 24];
    int t = tgt[row];
    float xt = x[(size_t)row * NCLASS + t];   // L1 hit: row just streamed

    float m = fmaxf(fmaxf(fmaxf(a.x, a.y), fmaxf(a.z, a.w)),
                    fmaxf(fmaxf(b.x, b.y), fmaxf(b.z, b.w)));
    m = fmaxf(m, fmaxf(fmaxf(c.x, c.y), fmaxf(c.z, c.w)));
    m = fmaxf(m, fmaxf(fmaxf(d.x, d.y), fmaxf(d.z, d.w)));
    m = fmaxf(m, __shfl_xor(m, 1, 64));
    m = fmaxf(m, __shfl_xor(m, 2, 64));
    m = fmaxf(m, __shfl_xor(m, 4, 64));

    float s = __expf(a.x - m) + __expf(a.y - m) + __expf(a.z - m) + __expf(a.w - m)
            + __expf(b.x - m) + __expf(b.y - m) + __expf(b.z - m) + __expf(b.w - m)
            + __expf(c.x - m) + __expf(c.y - m) + __expf(c.z - m) + __expf(c.w - m)
            + __expf(d.x - m) + __expf(d.y - m) + __expf(d.z - m) + __expf(d.w - m);
    s += __shfl_xor(s, 1, 64);
    s += __shfl_xor(s, 2, 64);
    s += __shfl_xor(s, 4, 64);

    if (j == 0) {
      float loss = fmaxf(__logf(s) + m - xt, 0.0f);
      losses[row] = loss;
      atomicAdd(&lh[__float_as_uint(loss) >> 20], 1u);
    }
  }
  __syncthreads();
  unsigned* h = hist1 + (size_t)(blockIdx.x & (NREP - 1)) * 4096;
  for (int i = threadIdx.x; i < 4096; i += 256) {
    unsigned v = lh[i];
    if (v) atomicAdd(&h[i], v);
  }
}

// Refine pass: histogram 10 more bits for elements matching the selected prefix.
__global__ __launch_bounds__(256) void hist_refine_kernel(
    const float* __restrict__ losses, const Scalars* __restrict__ sc,
    unsigned* __restrict__ hist, int N, int phase) {
  __shared__ unsigned lh[1024];
  for (int i = threadIdx.x; i < 1024; i += 256) lh[i] = 0;
  __syncthreads();
  unsigned prefix, shift;
  if (phase == 1) { prefix = sc->sel1; shift = 20; }
  else { prefix = (sc->sel1 << 10) | sc->sel2; shift = 10; }
  const unsigned sub_shift = shift - 10;
  const float4* L4 = (const float4*)losses;
  const int n4 = N >> 2;
  for (int idx = blockIdx.x * 256 + threadIdx.x; idx < n4; idx += gridDim.x * 256) {
    float4 v = L4[idx];
    unsigned b;
    b = __float_as_uint(v.x); if ((b >> shift) == prefix) atomicAdd(&lh[(b >> sub_shift) & 1023u], 1u);
    b = __float_as_uint(v.y); if ((b >> shift) == prefix) atomicAdd(&lh[(b >> sub_shift) & 1023u], 1u);
    b = __float_as_uint(v.z); if ((b >> shift) == prefix) atomicAdd(&lh[(b >> sub_shift) & 1023u], 1u);
    b = __float_as_uint(v.w); if ((b >> shift) == prefix) atomicAdd(&lh[(b >> sub_shift) & 1023u], 1u);
  }
  __syncthreads();
  unsigned* h = hist + (size_t)(blockIdx.x & (NREP - 1)) * 1024;
  for (int i = threadIdx.x; i < 1024; i += 256) {
    unsigned v = lh[i];
    if (v) atomicAdd(&h[i], v);
  }
}

// Single-wave descending-rank scan over NREP replicated histograms.
__global__ void scan_kernel(const unsigned* __restrict__ hist, Scalars* sc,
                            int nbins, int phase, int K) {
  const int lane = threadIdx.x;       // 64 threads
  const int bpt = nbins >> 6;         // bins per thread (64 or 16)
  const int Ktar = (phase == 0) ? K : sc->krem;

  // level 1: chunk sums (summing replicas), vectorized
  unsigned csum = 0;
  for (int rr = 0; rr < NREP; ++rr) {
    const uint4* h4 = (const uint4*)(hist + (size_t)rr * nbins + lane * bpt);
    for (int i = 0; i < (bpt >> 2); ++i) {
      uint4 q = h4[i];
      csum += q.x + q.y + q.z + q.w;
    }
  }
  unsigned suf = suffix_incl_u(csum, lane);
  unsigned long long mask = __ballot(suf >= (unsigned)Ktar);
  int c = 63 - __builtin_clzll(mask);
  unsigned above_excl = suf - csum;
  unsigned aboveC = __shfl(above_excl, c, 64);   // count strictly above chunk c

  // level 2: per-bin totals within chunk c
  unsigned h = 0;
  if (lane < bpt)
    for (int rr = 0; rr < NREP; ++rr) h += hist[(size_t)rr * nbins + c * bpt + lane];
  unsigned suf2 = suffix_incl_u(h, lane);
  unsigned long long mask2 = __ballot((lane < bpt) && (aboveC + suf2 >= (unsigned)Ktar));
  int u = 63 - __builtin_clzll(mask2);
  unsigned hU = __shfl(h, u, 64);
  unsigned suf2U = __shfl(suf2, u, 64);
  unsigned above = aboveC + suf2U - hU;          // count strictly above selected bin
  int bin = c * bpt + u;

  if (lane == 0) {
    if (phase == 0) {
      sc->sel1 = (unsigned)bin; sc->cnt_above = above; sc->krem = Ktar - (int)above;
    } else if (phase == 1) {
      sc->sel2 = (unsigned)bin; sc->cnt_above += above; sc->krem = Ktar - (int)above;
    } else {
      sc->thr_bits = (sc->sel1 << 20) | (sc->sel2 << 10) | (unsigned)bin;
      sc->cnt_above += above;
    }
  }
}

__global__ __launch_bounds__(256) void sum_topk_kernel(
    const float* __restrict__ losses, const Scalars* __restrict__ sc,
    double* __restrict__ partials, int N) {
  const unsigned thr = sc->thr_bits;
  double acc = 0.0;
  const float4* L4 = (const float4*)losses;
  const int n4 = N >> 2;
  for (int idx = blockIdx.x * 256 + threadIdx.x; idx < n4; idx += gridDim.x * 256) {
    float4 v = L4[idx];
    if (__float_as_uint(v.x) > thr) acc += v.x;
    if (__float_as_uint(v.y) > thr) acc += v.y;
    if (__float_as_uint(v.z) > thr) acc += v.z;
    if (__float_as_uint(v.w) > thr) acc += v.w;
  }
#pragma unroll
  for (int off = 32; off > 0; off >>= 1) acc += __shfl_down(acc, off, 64);
  __shared__ double wsum[4];
  if ((threadIdx.x & 63) == 0) wsum[threadIdx.x >> 6] = acc;
  __syncthreads();
  if (threadIdx.x == 0)
    partials[blockIdx.x] = wsum[0] + wsum[1] + wsum[2] + wsum[3];
}

__global__ void finalize_kernel(const double* __restrict__ partials,
                                const Scalars* __restrict__ sc,
                                float* __restrict__ out, int K, int npart) {
  const int lane = threadIdx.x;   // 64 threads
  double s = 0.0;
  for (int i = lane; i < npart; i += 64) s += partials[i];
#pragma unroll
  for (int off = 32; off > 0; off >>= 1) s += __shfl_down(s, off, 64);
  if (lane == 0) {
    double thr = (double)__uint_as_float(sc->thr_bits);
    double mean = (s + (double)(K - (int)sc->cnt_above) * thr) / (double)K;
    *out = (float)mean;
  }
}

extern "C" void kernel_launch(void* const* d_in, const int* in_sizes, int n_in,
                              void* d_out, int out_size, void* d_ws, size_t ws_size,
                              hipStream_t stream) {
  const float* x = (const float*)d_in[0];
  const int* tgt = (const int*)d_in[1];
  float* out = (float*)d_out;
  const int N = in_sizes[1];                 // 262144 rows
  const int K = (int)(0.7 * (double)N);      // 183500, matches Python int()

  char* ws = (char*)d_ws;
  const size_t OFF_H1 = (size_t)N * 4;                     // after losses (1 MiB)
  const size_t OFF_H2 = OFF_H1 + (size_t)NREP * 4096 * 4;  // +128 KiB
  const size_t OFF_H3 = OFF_H2 + (size_t)NREP * 1024 * 4;  // +32 KiB
  const size_t OFF_SC = OFF_H3 + (size_t)NREP * 1024 * 4;  // +32 KiB
  const size_t OFF_PT = OFF_SC + 256;

  float* losses = (float*)ws;
  unsigned* hist1 = (unsigned*)(ws + OFF_H1);
  unsigned* hist2 = (unsigned*)(ws + OFF_H2);
  unsigned* hist3 = (unsigned*)(ws + OFF_H3);
  Scalars* sc = (Scalars*)(ws + OFF_SC);
  double* partials = (double*)(ws + OFF_PT);

  hipMemsetAsync(ws + OFF_H1, 0, OFF_PT - OFF_H1, stream);

  loss_hist_kernel<<<512, 256, 0, stream>>>(x, tgt, losses, hist1, N);
  scan_kernel<<<1, 64, 0, stream>>>(hist1, sc, 4096, 0, K);
  hist_refine_kernel<<<64, 256, 0, stream>>>(losses, sc, hist2, N, 1);
  scan_kernel<<<1, 64, 0, stream>>>(hist2, sc, 1024, 1, K);
  hist_refine_kernel<<<64, 256, 0, stream>>>(losses, sc, hist3, N, 2);
  scan_kernel<<<1, 64, 0, stream>>>(hist3, sc, 1024, 2, K);
  sum_topk_kernel<<<128, 256, 0, stream>>>(losses, sc, partials, N);
  finalize_kernel<<<1, 64, 0, stream>>>(partials, sc, out, K, 128);
}